// Round 1
// baseline (1063.957 us; speedup 1.0000x reference)
//
#include <hip/hip_runtime.h>
#include <stdint.h>

#define B 8
#define NN 2000
#define EG 64000
#define FF 1024
#define DD 128

typedef short short8 __attribute__((ext_vector_type(8)));
typedef float f32x4 __attribute__((ext_vector_type(4)));

__device__ __forceinline__ unsigned short f2bf(float f) {
    union { float f; unsigned int u; } v; v.f = f;
    unsigned int u = v.u;
    unsigned int r = u + 0x7FFFu + ((u >> 16) & 1u);
    return (unsigned short)(r >> 16);
}
__device__ __forceinline__ float bf2f(unsigned short h) {
    union { unsigned int u; float f; } v; v.u = ((unsigned int)h) << 16;
    return v.f;
}
__device__ __forceinline__ float leaky(float v) { return v >= 0.0f ? v : 0.01f * v; }

// ---------------- small utility kernels ----------------
__global__ void k_fillf(float* __restrict__ p, float v, int n) {
    int i = blockIdx.x * 256 + threadIdx.x;
    if (i < n) p[i] = v;
}

__global__ void k_degcount(const int* __restrict__ ei, float* __restrict__ deg) {
    int i = blockIdx.x * 256 + threadIdx.x;
    if (i >= B * EG) return;
    int b = i / EG, e = i - b * EG;
    int t = ei[b * 2 * EG + EG + e];
    atomicAdd(&deg[b * NN + t], 1.0f);
}

__global__ void k_dinv(const float* __restrict__ deg, float* __restrict__ dinv, int n) {
    int i = blockIdx.x * 256 + threadIdx.x;
    if (i < n) dinv[i] = rsqrtf(deg[i]);
}

// per-batch exclusive scan of in-degree -> CSR offsets (+cursor init)
__global__ void k_scan(const float* __restrict__ deg, int* __restrict__ csr_off,
                       int* __restrict__ cursor) {
    int b = blockIdx.x, t = threadIdx.x;
    __shared__ int part[256];
    int loc[8];
    int s = 0;
#pragma unroll
    for (int i = 0; i < 8; ++i) {
        int n = t * 8 + i;
        int c = (n < NN) ? ((int)deg[b * NN + n] - 1) : 0;
        loc[i] = s;
        s += c;
    }
    part[t] = s;
    __syncthreads();
    for (int off = 1; off < 256; off <<= 1) {
        int v = (t >= off) ? part[t - off] : 0;
        __syncthreads();
        part[t] += v;
        __syncthreads();
    }
    int base = part[t] - s;
#pragma unroll
    for (int i = 0; i < 8; ++i) {
        int n = t * 8 + i;
        if (n < NN) {
            int o = base + loc[i];
            csr_off[b * (NN + 1) + n] = o;
            cursor[b * NN + n] = o;
        }
    }
    if (t == 255) csr_off[b * (NN + 1) + NN] = part[255];
}

__global__ void k_fillcsr(const int* __restrict__ ei, int* __restrict__ cursor,
                          int* __restrict__ esrc) {
    int i = blockIdx.x * 256 + threadIdx.x;
    if (i >= B * EG) return;
    int b = i / EG, e = i - b * EG;
    int s = ei[b * 2 * EG + e];
    int t = ei[b * 2 * EG + EG + e];
    int pos = atomicAdd(&cursor[b * NN + t], 1);
    esrc[b * EG + pos] = s;
}

__global__ void k_convx(const float* __restrict__ x, unsigned short* __restrict__ xb, int n4) {
    int i = blockIdx.x * 256 + threadIdx.x;
    if (i >= n4) return;
    float4 v = ((const float4*)x)[i];
    ushort4 o;
    o.x = f2bf(v.x); o.y = f2bf(v.y); o.z = f2bf(v.z); o.w = f2bf(v.w);
    ((ushort4*)xb)[i] = o;
}

// transpose+convert Wg[F][F] fp32 -> wT[n][k] bf16
__global__ void k_wT(const float* __restrict__ Wg, unsigned short* __restrict__ wT) {
    __shared__ float tile[32][33];
    int tx = threadIdx.x, ty = threadIdx.y;  // 32 x 8
    int k0 = blockIdx.y * 32, n0 = blockIdx.x * 32;
#pragma unroll
    for (int r = 0; r < 4; ++r) {
        int row = ty + r * 8;
        tile[row][tx] = Wg[(k0 + row) * FF + n0 + tx];
    }
    __syncthreads();
#pragma unroll
    for (int r = 0; r < 4; ++r) {
        int row = ty + r * 8;
        wT[(n0 + row) * FF + k0 + tx] = f2bf(tile[tx][row]);
    }
}

// ---------------- bf16 MFMA GEMM: H = A(16000x1024) * W, W given as wT[n][k] ----------------
#define LS 40  // LDS row stride in bf16 elems (80B) -> breaks b128 bank conflicts
__launch_bounds__(256) __global__
void k_gemm(const unsigned short* __restrict__ Abf, const unsigned short* __restrict__ Bbf,
            unsigned short* __restrict__ Hbf) {
    __shared__ __align__(16) unsigned short As[128 * LS];
    __shared__ __align__(16) unsigned short Bs[128 * LS];
    int tid = threadIdx.x;
    int lane = tid & 63, wave = tid >> 6;
    int wr = wave >> 1, wc = wave & 1;
    int m0 = blockIdx.x * 128, n0 = blockIdx.y * 128;
    int q = lane >> 4, l15 = lane & 15;
    int sr = tid >> 2, sc = tid & 3;  // staging: row 0..63 (x2 passes), 16B chunk 0..3

    f32x4 acc[4][4];
#pragma unroll
    for (int i = 0; i < 4; ++i)
#pragma unroll
        for (int j = 0; j < 4; ++j) acc[i][j] = (f32x4){0.f, 0.f, 0.f, 0.f};

    for (int kt = 0; kt < 32; ++kt) {
        int kb = kt * 32;
#pragma unroll
        for (int p = 0; p < 2; ++p) {
            int r = p * 64 + sr;
            *(uint4*)&As[r * LS + sc * 8] = *(const uint4*)&Abf[(size_t)(m0 + r) * FF + kb + sc * 8];
            *(uint4*)&Bs[r * LS + sc * 8] = *(const uint4*)&Bbf[(size_t)(n0 + r) * FF + kb + sc * 8];
        }
        __syncthreads();
        short8 fa[4], fb[4];
#pragma unroll
        for (int i = 0; i < 4; ++i)
            fa[i] = *(const short8*)&As[(wr * 64 + i * 16 + l15) * LS + q * 8];
#pragma unroll
        for (int j = 0; j < 4; ++j)
            fb[j] = *(const short8*)&Bs[(wc * 64 + j * 16 + l15) * LS + q * 8];
#pragma unroll
        for (int i = 0; i < 4; ++i)
#pragma unroll
            for (int j = 0; j < 4; ++j)
                acc[i][j] = __builtin_amdgcn_mfma_f32_16x16x32_bf16(fa[i], fb[j], acc[i][j], 0, 0, 0);
        __syncthreads();
    }
#pragma unroll
    for (int i = 0; i < 4; ++i) {
#pragma unroll
        for (int j = 0; j < 4; ++j) {
            int n = n0 + wc * 64 + j * 16 + l15;
#pragma unroll
            for (int v = 0; v < 4; ++v) {
                int m = m0 + wr * 64 + i * 16 + q * 4 + v;
                Hbf[(size_t)m * FF + n] = f2bf(acc[i][j][v]);
            }
        }
    }
}

// ---------------- fused aggregation + bias + leaky + node-sum ----------------
__launch_bounds__(256) __global__
void k_aggreduce(const unsigned short* __restrict__ Hbf, const int* __restrict__ csr_off,
                 const int* __restrict__ esrc, const float* __restrict__ dinv,
                 const float* __restrict__ bg, float* __restrict__ gsum) {
    int blk = blockIdx.x;
    int b = blk / 125, chunk = blk - b * 125;
    int n0 = chunk * 16;
    int tid = threadIdx.x;
    int f0 = tid * 4;
    float bgv[4];
#pragma unroll
    for (int i = 0; i < 4; ++i) bgv[i] = bg[f0 + i];
    float bsum[4] = {0.f, 0.f, 0.f, 0.f};

    for (int nn = 0; nn < 16; ++nn) {
        int n = n0 + nn;
        float dn = dinv[b * NN + n];
        float racc[4];
        ushort4 hv = *(const ushort4*)&Hbf[(size_t)(b * NN + n) * FF + f0];
        float ws = dn * dn;  // self-loop weight 1/deg
        racc[0] = ws * bf2f(hv.x);
        racc[1] = ws * bf2f(hv.y);
        racc[2] = ws * bf2f(hv.z);
        racc[3] = ws * bf2f(hv.w);
        int beg = csr_off[b * (NN + 1) + n];
        int end = csr_off[b * (NN + 1) + n + 1];
        for (int j = beg; j < end; ++j) {
            int s = esrc[b * EG + j];
            float w = dinv[b * NN + s] * dn;
            ushort4 sv = *(const ushort4*)&Hbf[(size_t)(b * NN + s) * FF + f0];
            racc[0] += w * bf2f(sv.x);
            racc[1] += w * bf2f(sv.y);
            racc[2] += w * bf2f(sv.z);
            racc[3] += w * bf2f(sv.w);
        }
#pragma unroll
        for (int i = 0; i < 4; ++i) bsum[i] += leaky(racc[i] + bgv[i]);
    }
#pragma unroll
    for (int i = 0; i < 4; ++i) atomicAdd(&gsum[b * FF + f0 + i], bsum[i]);
}

// g[b,d] = leaky( (gsum[b,:]/N) @ Wf[:,d] + bf[d] )
__global__ void k_fc(const float* __restrict__ gsum, const float* __restrict__ Wf,
                     const float* __restrict__ bfv, float* __restrict__ g) {
    int b = blockIdx.x, d = threadIdx.x;  // 128 threads
    float acc = 0.f;
#pragma unroll 8
    for (int f = 0; f < FF; ++f) acc += gsum[b * FF + f] * Wf[f * DD + d];
    acc = acc * (1.0f / (float)NN) + bfv[d];
    g[b * DD + d] = leaky(acc);
}

__launch_bounds__(256) __global__
void k_head(const float* __restrict__ g, const float* __restrict__ W1, const float* __restrict__ b1,
            const float* __restrict__ W2, const float* __restrict__ b2,
            const float* __restrict__ Wo, const float* __restrict__ bo, float* __restrict__ out) {
    __shared__ float xc[8][256];
    __shared__ float l1[8][256];
    __shared__ float l2[8][64];
    int t = threadIdx.x;
#pragma unroll
    for (int i = 0; i < 8; ++i) {
        int idx = i * 256 + t;
        int b = idx >> 8, j = idx & 255;
        xc[b][j] = (j < DD) ? g[b * DD + j] : g[B * DD + b * DD + (j - DD)];
    }
    __syncthreads();
    {
        int j = t;
        float a[8];
#pragma unroll
        for (int b = 0; b < 8; ++b) a[b] = b1[j];
        for (int k = 0; k < 256; ++k) {
            float w = W1[k * 256 + j];
#pragma unroll
            for (int b = 0; b < 8; ++b) a[b] += xc[b][k] * w;
        }
#pragma unroll
        for (int b = 0; b < 8; ++b) l1[b][j] = leaky(a[b]);
    }
    __syncthreads();
    if (t < 64) {
        int j = t;
        float a[8];
#pragma unroll
        for (int b = 0; b < 8; ++b) a[b] = b2[j];
        for (int k = 0; k < 256; ++k) {
            float w = W2[k * 64 + j];
#pragma unroll
            for (int b = 0; b < 8; ++b) a[b] += l1[b][k] * w;
        }
#pragma unroll
        for (int b = 0; b < 8; ++b) l2[b][j] = leaky(a[b]);
    }
    __syncthreads();
    if (t < 8) {
        float a = bo[0];
        for (int k = 0; k < 64; ++k) a += l2[t][k] * Wo[k];
        out[t] = 1.0f / (1.0f + expf(-a));
    }
}

extern "C" void kernel_launch(void* const* d_in, const int* in_sizes, int n_in,
                              void* d_out, int out_size, void* d_ws, size_t ws_size,
                              hipStream_t stream) {
    const float* x1  = (const float*)d_in[0];
    const int*   ei1 = (const int*)d_in[1];
    const float* x2  = (const float*)d_in[2];
    const int*   ei2 = (const int*)d_in[3];
    const float* Wg1 = (const float*)d_in[4];
    const float* bg1 = (const float*)d_in[5];
    const float* Wf1 = (const float*)d_in[6];
    const float* bf1 = (const float*)d_in[7];
    const float* Wg2 = (const float*)d_in[8];
    const float* bg2 = (const float*)d_in[9];
    const float* Wf2 = (const float*)d_in[10];
    const float* bf2 = (const float*)d_in[11];
    const float* W1  = (const float*)d_in[12];
    const float* b1  = (const float*)d_in[13];
    const float* W2  = (const float*)d_in[14];
    const float* b2  = (const float*)d_in[15];
    const float* Wo  = (const float*)d_in[16];
    const float* bo  = (const float*)d_in[17];
    float* out = (float*)d_out;

    char* w = (char*)d_ws;
    auto alloc = [&](size_t bytes) {
        char* p = w;
        w += (bytes + 255) & ~(size_t)255;
        return p;
    };
    float* deg      = (float*)alloc((size_t)B * NN * 4);
    float* dinv     = (float*)alloc((size_t)B * NN * 4);
    int* csr_off    = (int*)alloc((size_t)B * (NN + 1) * 4);
    int* cursor     = (int*)alloc((size_t)B * NN * 4);
    int* esrc       = (int*)alloc((size_t)B * EG * 4);
    unsigned short* xbf = (unsigned short*)alloc((size_t)B * NN * FF * 2);
    unsigned short* wT  = (unsigned short*)alloc((size_t)FF * FF * 2);
    unsigned short* hbf = (unsigned short*)alloc((size_t)B * NN * FF * 2);
    float* gsum     = (float*)alloc((size_t)2 * B * FF * 4);
    float* g12      = (float*)alloc((size_t)2 * B * DD * 4);

    k_fillf<<<(2 * B * FF + 255) / 256, 256, 0, stream>>>(gsum, 0.0f, 2 * B * FF);

    const float* xs[2]  = {x1, x2};
    const int*   eis[2] = {ei1, ei2};
    const float* Wgs[2] = {Wg1, Wg2};
    const float* bgs[2] = {bg1, bg2};
    const float* Wfs[2] = {Wf1, Wf2};
    const float* bfs[2] = {bf1, bf2};

    for (int br = 0; br < 2; ++br) {
        k_fillf<<<(B * NN + 255) / 256, 256, 0, stream>>>(deg, 1.0f, B * NN);
        k_degcount<<<(B * EG + 255) / 256, 256, 0, stream>>>(eis[br], deg);
        k_scan<<<B, 256, 0, stream>>>(deg, csr_off, cursor);
        k_dinv<<<(B * NN + 255) / 256, 256, 0, stream>>>(deg, dinv, B * NN);
        k_fillcsr<<<(B * EG + 255) / 256, 256, 0, stream>>>(eis[br], cursor, esrc);
        k_convx<<<(B * NN * FF / 4 + 255) / 256, 256, 0, stream>>>(xs[br], xbf, B * NN * FF / 4);
        k_wT<<<dim3(32, 32), dim3(32, 8), 0, stream>>>(Wgs[br], wT);
        k_gemm<<<dim3(125, 8), 256, 0, stream>>>(xbf, wT, hbf);
        k_aggreduce<<<B * 125, 256, 0, stream>>>(hbf, csr_off, esrc, dinv, bgs[br],
                                                 gsum + (size_t)br * B * FF);
        k_fc<<<B, DD, 0, stream>>>(gsum + (size_t)br * B * FF, Wfs[br], bfs[br],
                                   g12 + (size_t)br * B * DD);
    }
    k_head<<<1, 256, 0, stream>>>(g12, W1, b1, W2, b2, Wo, bo, out);
}

// Round 2
// 841.464 us; speedup vs baseline: 1.2644x; 1.2644x over previous
//
#include <hip/hip_runtime.h>
#include <stdint.h>

#define B 8
#define NN 2000
#define EG 64000
#define FF 1024
#define DD 128

typedef short short8 __attribute__((ext_vector_type(8)));
typedef float f32x4 __attribute__((ext_vector_type(4)));

__device__ __forceinline__ unsigned short f2bf(float f) {
    union { float f; unsigned int u; } v; v.f = f;
    unsigned int u = v.u;
    unsigned int r = u + 0x7FFFu + ((u >> 16) & 1u);
    return (unsigned short)(r >> 16);
}
__device__ __forceinline__ float bf2f(unsigned short h) {
    union { unsigned int u; float f; } v; v.u = ((unsigned int)h) << 16;
    return v.f;
}
__device__ __forceinline__ float leaky(float v) { return v >= 0.0f ? v : 0.01f * v; }

// unpack uint4 = 8 bf16 and fma into r[0..7] with weight w
__device__ __forceinline__ void acc8(float* __restrict__ r, float w, uint4 v) {
    union { unsigned int u; float f; } c;
    unsigned int u;
    u = v.x; c.u = u << 16; r[0] += w * c.f; c.u = u & 0xffff0000u; r[1] += w * c.f;
    u = v.y; c.u = u << 16; r[2] += w * c.f; c.u = u & 0xffff0000u; r[3] += w * c.f;
    u = v.z; c.u = u << 16; r[4] += w * c.f; c.u = u & 0xffff0000u; r[5] += w * c.f;
    u = v.w; c.u = u << 16; r[6] += w * c.f; c.u = u & 0xffff0000u; r[7] += w * c.f;
}

// ---------------- small utility kernels ----------------
__global__ void k_fillf(float* __restrict__ p, float v, int n) {
    int i = blockIdx.x * 256 + threadIdx.x;
    if (i < n) p[i] = v;
}

__global__ void k_degcount(const int* __restrict__ ei, float* __restrict__ deg) {
    int i = blockIdx.x * 256 + threadIdx.x;
    if (i >= B * EG) return;
    int b = i / EG, e = i - b * EG;
    int t = ei[b * 2 * EG + EG + e];
    atomicAdd(&deg[b * NN + t], 1.0f);
}

__global__ void k_dinv(const float* __restrict__ deg, float* __restrict__ dinv, int n) {
    int i = blockIdx.x * 256 + threadIdx.x;
    if (i < n) dinv[i] = rsqrtf(deg[i]);
}

// per-batch exclusive scan of in-degree -> CSR offsets (+cursor init)
__global__ void k_scan(const float* __restrict__ deg, int* __restrict__ csr_off,
                       int* __restrict__ cursor) {
    int b = blockIdx.x, t = threadIdx.x;
    __shared__ int part[256];
    int loc[8];
    int s = 0;
#pragma unroll
    for (int i = 0; i < 8; ++i) {
        int n = t * 8 + i;
        int c = (n < NN) ? ((int)deg[b * NN + n] - 1) : 0;
        loc[i] = s;
        s += c;
    }
    part[t] = s;
    __syncthreads();
    for (int off = 1; off < 256; off <<= 1) {
        int v = (t >= off) ? part[t - off] : 0;
        __syncthreads();
        part[t] += v;
        __syncthreads();
    }
    int base = part[t] - s;
#pragma unroll
    for (int i = 0; i < 8; ++i) {
        int n = t * 8 + i;
        if (n < NN) {
            int o = base + loc[i];
            csr_off[b * (NN + 1) + n] = o;
            cursor[b * NN + n] = o;
        }
    }
    if (t == 255) csr_off[b * (NN + 1) + NN] = part[255];
}

// fill CSR source list + per-edge norm weight (dinv must be ready)
__global__ void k_fillcsr(const int* __restrict__ ei, int* __restrict__ cursor,
                          const float* __restrict__ dinv, int* __restrict__ esrc,
                          float* __restrict__ ewt) {
    int i = blockIdx.x * 256 + threadIdx.x;
    if (i >= B * EG) return;
    int b = i / EG, e = i - b * EG;
    int s = ei[b * 2 * EG + e];
    int t = ei[b * 2 * EG + EG + e];
    int pos = atomicAdd(&cursor[b * NN + t], 1);
    esrc[b * EG + pos] = s;
    ewt[b * EG + pos] = dinv[b * NN + s] * dinv[b * NN + t];
}

__global__ void k_convx(const float* __restrict__ x, unsigned short* __restrict__ xb, int n4) {
    int i = blockIdx.x * 256 + threadIdx.x;
    if (i >= n4) return;
    float4 v = ((const float4*)x)[i];
    ushort4 o;
    o.x = f2bf(v.x); o.y = f2bf(v.y); o.z = f2bf(v.z); o.w = f2bf(v.w);
    ((ushort4*)xb)[i] = o;
}

// transpose+convert Wg[F][F] fp32 -> wT[n][k] bf16
__global__ void k_wT(const float* __restrict__ Wg, unsigned short* __restrict__ wT) {
    __shared__ float tile[32][33];
    int tx = threadIdx.x, ty = threadIdx.y;  // 32 x 8
    int k0 = blockIdx.y * 32, n0 = blockIdx.x * 32;
#pragma unroll
    for (int r = 0; r < 4; ++r) {
        int row = ty + r * 8;
        tile[row][tx] = Wg[(k0 + row) * FF + n0 + tx];
    }
    __syncthreads();
#pragma unroll
    for (int r = 0; r < 4; ++r) {
        int row = ty + r * 8;
        wT[(n0 + row) * FF + k0 + tx] = f2bf(tile[tx][row]);
    }
}

// ---------------- bf16 MFMA GEMM: H = A(16000x1024) * W, W given as wT[n][k] ----------------
#define LS 40  // LDS row stride in bf16 elems (80B) -> breaks b128 bank conflicts
__launch_bounds__(256) __global__
void k_gemm(const unsigned short* __restrict__ Abf, const unsigned short* __restrict__ Bbf,
            unsigned short* __restrict__ Hbf) {
    __shared__ __align__(16) unsigned short As[128 * LS];
    __shared__ __align__(16) unsigned short Bs[128 * LS];
    int tid = threadIdx.x;
    int lane = tid & 63, wave = tid >> 6;
    int wr = wave >> 1, wc = wave & 1;
    int m0 = blockIdx.x * 128, n0 = blockIdx.y * 128;
    int q = lane >> 4, l15 = lane & 15;
    int sr = tid >> 2, sc = tid & 3;  // staging: row 0..63 (x2 passes), 16B chunk 0..3

    f32x4 acc[4][4];
#pragma unroll
    for (int i = 0; i < 4; ++i)
#pragma unroll
        for (int j = 0; j < 4; ++j) acc[i][j] = (f32x4){0.f, 0.f, 0.f, 0.f};

    for (int kt = 0; kt < 32; ++kt) {
        int kb = kt * 32;
#pragma unroll
        for (int p = 0; p < 2; ++p) {
            int r = p * 64 + sr;
            *(uint4*)&As[r * LS + sc * 8] = *(const uint4*)&Abf[(size_t)(m0 + r) * FF + kb + sc * 8];
            *(uint4*)&Bs[r * LS + sc * 8] = *(const uint4*)&Bbf[(size_t)(n0 + r) * FF + kb + sc * 8];
        }
        __syncthreads();
        short8 fa[4], fb[4];
#pragma unroll
        for (int i = 0; i < 4; ++i)
            fa[i] = *(const short8*)&As[(wr * 64 + i * 16 + l15) * LS + q * 8];
#pragma unroll
        for (int j = 0; j < 4; ++j)
            fb[j] = *(const short8*)&Bs[(wc * 64 + j * 16 + l15) * LS + q * 8];
#pragma unroll
        for (int i = 0; i < 4; ++i)
#pragma unroll
            for (int j = 0; j < 4; ++j)
                acc[i][j] = __builtin_amdgcn_mfma_f32_16x16x32_bf16(fa[i], fb[j], acc[i][j], 0, 0, 0);
        __syncthreads();
    }
#pragma unroll
    for (int i = 0; i < 4; ++i) {
#pragma unroll
        for (int j = 0; j < 4; ++j) {
            int n = n0 + wc * 64 + j * 16 + l15;
#pragma unroll
            for (int v = 0; v < 4; ++v) {
                int m = m0 + wr * 64 + i * 16 + q * 4 + v;
                Hbf[(size_t)m * FF + n] = f2bf(acc[i][j][v]);
            }
        }
    }
}

// ---------------- fused aggregation + bias + leaky + node-sum ----------------
// grid: 1000 blocks; batch = blockIdx & 7 (XCD-pinned), chunk of 16 nodes each.
// 2 teams of 128 threads; each team: one node at a time, lane covers 8 feats (16B).
__launch_bounds__(256) __global__
void k_aggreduce(const unsigned short* __restrict__ Hbf, const int* __restrict__ csr_off,
                 const int* __restrict__ esrc, const float* __restrict__ ewt,
                 const float* __restrict__ dinv, const float* __restrict__ bg,
                 float* __restrict__ gsum) {
    int blk = blockIdx.x;
    int b = blk & 7;          // XCD swizzle: all blocks of batch b land on XCD b
    int chunk = blk >> 3;     // 0..124
    int tid = threadIdx.x;
    int team = tid >> 7;      // 0,1
    int lt = tid & 127;
    int f0 = lt * 8;
    int n0 = chunk * 16 + team * 8;
    const unsigned short* Hb = Hbf + (size_t)b * NN * FF;
    const int* es = esrc + (size_t)b * EG;
    const float* ew = ewt + (size_t)b * EG;

    float bgv[8];
#pragma unroll
    for (int i = 0; i < 8; ++i) bgv[i] = bg[f0 + i];
    float bsum[8] = {0.f, 0.f, 0.f, 0.f, 0.f, 0.f, 0.f, 0.f};

    for (int nn = 0; nn < 8; ++nn) {
        int n = n0 + nn;
        float dn = dinv[b * NN + n];
        int beg = csr_off[b * (NN + 1) + n];
        int end = csr_off[b * (NN + 1) + n + 1];
        float racc[8] = {0.f, 0.f, 0.f, 0.f, 0.f, 0.f, 0.f, 0.f};
        // self-loop (weight 1/deg)
        {
            uint4 sv = *(const uint4*)&Hb[(size_t)n * FF + f0];
            acc8(racc, dn * dn, sv);
        }
        int j = beg;
        for (; j + 4 <= end; j += 4) {
            int s0 = es[j], s1 = es[j + 1], s2 = es[j + 2], s3 = es[j + 3];
            float w0 = ew[j], w1 = ew[j + 1], w2 = ew[j + 2], w3 = ew[j + 3];
            uint4 v0 = *(const uint4*)&Hb[(size_t)s0 * FF + f0];
            uint4 v1 = *(const uint4*)&Hb[(size_t)s1 * FF + f0];
            uint4 v2 = *(const uint4*)&Hb[(size_t)s2 * FF + f0];
            uint4 v3 = *(const uint4*)&Hb[(size_t)s3 * FF + f0];
            acc8(racc, w0, v0);
            acc8(racc, w1, v1);
            acc8(racc, w2, v2);
            acc8(racc, w3, v3);
        }
        for (; j < end; ++j) {
            int s = es[j];
            float w = ew[j];
            uint4 v = *(const uint4*)&Hb[(size_t)s * FF + f0];
            acc8(racc, w, v);
        }
#pragma unroll
        for (int i = 0; i < 8; ++i) bsum[i] += leaky(racc[i] + bgv[i]);
    }

    // combine the two teams, then one atomic set per lane of team 0
    __shared__ float red[128 * 8];
    if (team == 1) {
#pragma unroll
        for (int i = 0; i < 8; ++i) red[lt * 8 + i] = bsum[i];
    }
    __syncthreads();
    if (team == 0) {
#pragma unroll
        for (int i = 0; i < 8; ++i)
            atomicAdd(&gsum[b * FF + f0 + i], bsum[i] + red[lt * 8 + i]);
    }
}

// g[b,d] = leaky( (gsum[b,:]/N) @ Wf[:,d] + bf[d] )
__global__ void k_fc(const float* __restrict__ gsum, const float* __restrict__ Wf,
                     const float* __restrict__ bfv, float* __restrict__ g) {
    int b = blockIdx.x, d = threadIdx.x;  // 128 threads
    float acc = 0.f;
#pragma unroll 8
    for (int f = 0; f < FF; ++f) acc += gsum[b * FF + f] * Wf[f * DD + d];
    acc = acc * (1.0f / (float)NN) + bfv[d];
    g[b * DD + d] = leaky(acc);
}

__launch_bounds__(256) __global__
void k_head(const float* __restrict__ g, const float* __restrict__ W1, const float* __restrict__ b1,
            const float* __restrict__ W2, const float* __restrict__ b2,
            const float* __restrict__ Wo, const float* __restrict__ bo, float* __restrict__ out) {
    __shared__ float xc[8][256];
    __shared__ float l1[8][256];
    __shared__ float l2[8][64];
    int t = threadIdx.x;
#pragma unroll
    for (int i = 0; i < 8; ++i) {
        int idx = i * 256 + t;
        int b = idx >> 8, j = idx & 255;
        xc[b][j] = (j < DD) ? g[b * DD + j] : g[B * DD + b * DD + (j - DD)];
    }
    __syncthreads();
    {
        int j = t;
        float a[8];
#pragma unroll
        for (int b = 0; b < 8; ++b) a[b] = b1[j];
        for (int k = 0; k < 256; ++k) {
            float w = W1[k * 256 + j];
#pragma unroll
            for (int b = 0; b < 8; ++b) a[b] += xc[b][k] * w;
        }
#pragma unroll
        for (int b = 0; b < 8; ++b) l1[b][j] = leaky(a[b]);
    }
    __syncthreads();
    if (t < 64) {
        int j = t;
        float a[8];
#pragma unroll
        for (int b = 0; b < 8; ++b) a[b] = b2[j];
        for (int k = 0; k < 256; ++k) {
            float w = W2[k * 64 + j];
#pragma unroll
            for (int b = 0; b < 8; ++b) a[b] += l1[b][k] * w;
        }
#pragma unroll
        for (int b = 0; b < 8; ++b) l2[b][j] = leaky(a[b]);
    }
    __syncthreads();
    if (t < 8) {
        float a = bo[0];
        for (int k = 0; k < 64; ++k) a += l2[t][k] * Wo[k];
        out[t] = 1.0f / (1.0f + expf(-a));
    }
}

extern "C" void kernel_launch(void* const* d_in, const int* in_sizes, int n_in,
                              void* d_out, int out_size, void* d_ws, size_t ws_size,
                              hipStream_t stream) {
    const float* x1  = (const float*)d_in[0];
    const int*   ei1 = (const int*)d_in[1];
    const float* x2  = (const float*)d_in[2];
    const int*   ei2 = (const int*)d_in[3];
    const float* Wg1 = (const float*)d_in[4];
    const float* bg1 = (const float*)d_in[5];
    const float* Wf1 = (const float*)d_in[6];
    const float* bf1 = (const float*)d_in[7];
    const float* Wg2 = (const float*)d_in[8];
    const float* bg2 = (const float*)d_in[9];
    const float* Wf2 = (const float*)d_in[10];
    const float* bf2 = (const float*)d_in[11];
    const float* W1  = (const float*)d_in[12];
    const float* b1  = (const float*)d_in[13];
    const float* W2  = (const float*)d_in[14];
    const float* b2  = (const float*)d_in[15];
    const float* Wo  = (const float*)d_in[16];
    const float* bo  = (const float*)d_in[17];
    float* out = (float*)d_out;

    char* w = (char*)d_ws;
    auto alloc = [&](size_t bytes) {
        char* p = w;
        w += (bytes + 255) & ~(size_t)255;
        return p;
    };
    float* deg      = (float*)alloc((size_t)B * NN * 4);
    float* dinv     = (float*)alloc((size_t)B * NN * 4);
    int* csr_off    = (int*)alloc((size_t)B * (NN + 1) * 4);
    int* cursor     = (int*)alloc((size_t)B * NN * 4);
    int* esrc       = (int*)alloc((size_t)B * EG * 4);
    float* ewt      = (float*)alloc((size_t)B * EG * 4);
    unsigned short* xbf = (unsigned short*)alloc((size_t)B * NN * FF * 2);
    unsigned short* wT  = (unsigned short*)alloc((size_t)FF * FF * 2);
    unsigned short* hbf = (unsigned short*)alloc((size_t)B * NN * FF * 2);
    float* gsum     = (float*)alloc((size_t)2 * B * FF * 4);
    float* g12      = (float*)alloc((size_t)2 * B * DD * 4);

    k_fillf<<<(2 * B * FF + 255) / 256, 256, 0, stream>>>(gsum, 0.0f, 2 * B * FF);

    const float* xs[2]  = {x1, x2};
    const int*   eis[2] = {ei1, ei2};
    const float* Wgs[2] = {Wg1, Wg2};
    const float* bgs[2] = {bg1, bg2};
    const float* Wfs[2] = {Wf1, Wf2};
    const float* bfs[2] = {bf1, bf2};

    for (int br = 0; br < 2; ++br) {
        k_fillf<<<(B * NN + 255) / 256, 256, 0, stream>>>(deg, 1.0f, B * NN);
        k_degcount<<<(B * EG + 255) / 256, 256, 0, stream>>>(eis[br], deg);
        k_scan<<<B, 256, 0, stream>>>(deg, csr_off, cursor);
        k_dinv<<<(B * NN + 255) / 256, 256, 0, stream>>>(deg, dinv, B * NN);
        k_fillcsr<<<(B * EG + 255) / 256, 256, 0, stream>>>(eis[br], cursor, dinv, esrc, ewt);
        k_convx<<<(B * NN * FF / 4 + 255) / 256, 256, 0, stream>>>(xs[br], xbf, B * NN * FF / 4);
        k_wT<<<dim3(32, 32), dim3(32, 8), 0, stream>>>(Wgs[br], wT);
        k_gemm<<<dim3(125, 8), 256, 0, stream>>>(xbf, wT, hbf);
        k_aggreduce<<<B * 125, 256, 0, stream>>>(hbf, csr_off, esrc, ewt, dinv, bgs[br],
                                                 gsum + (size_t)br * B * FF);
        k_fc<<<B, DD, 0, stream>>>(gsum + (size_t)br * B * FF, Wfs[br], bfs[br],
                                   g12 + (size_t)br * B * DD);
    }
    k_head<<<1, 256, 0, stream>>>(g12, W1, b1, W2, b2, Wo, bo, out);
}